// Round 8
// baseline (50.500 us; speedup 1.0000x reference)
//
#include <hip/hip_runtime.h>
#include <math.h>
#include <stdint.h>

#define D_MODEL 128
#define EDGE_DIM 9
#define HIDDEN 256
#define BATCH 2
#define NN 512

#define TI 4     // i-tile in kernel 2
#define TJ 32    // j-tile in kernel 2

typedef _Float16 h2v    __attribute__((ext_vector_type(2)));
typedef __fp16   fp16x2 __attribute__((ext_vector_type(2)));
typedef _Float16 f16x8  __attribute__((ext_vector_type(8)));
typedef float    f32x4  __attribute__((ext_vector_type(4)));

struct H8 { h2v v[4]; };   // 16B = one MFMA A/B fragment

__device__ __forceinline__ uint32_t h2u(h2v v) { return __builtin_bit_cast(uint32_t, v); }
__device__ __forceinline__ h2v u2h(uint32_t u) { return __builtin_bit_cast(h2v, u); }
__device__ __forceinline__ h2v pkrtz(float a, float b) {
    return __builtin_bit_cast(h2v, __builtin_amdgcn_cvt_pkrtz(a, b));
}
__device__ __forceinline__ h2v relu2(h2v v) {
    h2v z = {(_Float16)0.0f, (_Float16)0.0f};
    return __builtin_elementwise_max(v, z);
}
__device__ __forceinline__ float fdot2(h2v a, h2v b, float c) {
    return __builtin_amdgcn_fdot2(__builtin_bit_cast(fp16x2, a),
                                  __builtin_bit_cast(fp16x2, b), c, false);
}
__device__ __forceinline__ float sigmoidf_(float x) { return 1.f / (1.f + expf(-x)); }

// ---------------------------------------------------------------------------
// Kernel 1 (MFMA): C = z @ W for one of {Wo1, We_i, We_j} per block.y.
// (Unchanged from round 7 — dropped node from ~20 us to noise level.)
// ---------------------------------------------------------------------------
__global__ __launch_bounds__(512) void node_mfma_kernel(
    const float* __restrict__ z,      // (B*N, 128)
    const float* __restrict__ Wo1,    // (128,256)
    const float* __restrict__ bo1,    // (256)
    const float* __restrict__ Wo2,    // (256,1)
    const float* __restrict__ bo2,    // (1)
    const float* __restrict__ We_i,   // (128,256)
    const float* __restrict__ We_j,   // (128,256)
    const float* __restrict__ be1,    // (256)
    float* __restrict__ organ_out,    // (B*N)
    uint32_t* __restrict__ pi_h,      // (B*N,128) half2, includes +be1
    uint32_t* __restrict__ pj_h)      // (B*N,128) half2
{
    __shared__ uint32_t Wlds[256][68];     // ~69.6 KiB, f16-pair, [h][d2^swz]
    __shared__ float org_part[32][4];

    const int t    = threadIdx.x;
    const int lane = t & 63;
    const int wave = t >> 6;
    const int rb   = blockIdx.x;           // row-block: rows 32*rb..32*rb+31
    const int m    = blockIdx.y;           // 0 = Wo1/organ, 1 = We_i/pi, 2 = We_j/pj

    const float* __restrict__ W = (m == 0) ? Wo1 : (m == 1) ? We_i : We_j;

    // ---- stage W -> LDS f16, transposed, swizzled ----
    for (int idx = t; idx < 64 * 256; idx += 512) {
        const int d2 = idx >> 8;           // 0..63 (d-pair)
        const int h  = idx & 255;          // coalesced over h
        const float wlo = W[(2 * d2) * 256 + h];
        const float whi = W[(2 * d2 + 1) * 256 + h];
        Wlds[h][d2 ^ ((h & 7) << 3)] = h2u(pkrtz(wlo, whi));
    }

    // ---- A-frags straight from global ----
    const int rt = wave & 1;               // row-tile
    const int cg = wave >> 1;              // col-group (4 tiles of 16)
    const int kg = lane >> 4;              // k-subgroup
    const int row = rb * 32 + rt * 16 + (lane & 15);

    f16x8 A[4];
#pragma unroll
    for (int kt = 0; kt < 4; ++kt) {
        const float4 za = *(const float4*)&z[(size_t)row * 128 + kt * 32 + kg * 8];
        const float4 zb = *(const float4*)&z[(size_t)row * 128 + kt * 32 + kg * 8 + 4];
        H8 a;
        a.v[0] = pkrtz(za.x, za.y); a.v[1] = pkrtz(za.z, za.w);
        a.v[2] = pkrtz(zb.x, zb.y); a.v[3] = pkrtz(zb.z, zb.w);
        A[kt] = __builtin_bit_cast(f16x8, a);
    }

    __syncthreads();

    // ---- MFMA main: 4 col-tiles x 4 k-tiles ----
    f32x4 C[4];
#pragma unroll
    for (int ct = 0; ct < 4; ++ct) {
        const int col = (cg * 4 + ct) * 16 + (lane & 15);
        C[ct] = (f32x4){0.f, 0.f, 0.f, 0.f};
#pragma unroll
        for (int kt = 0; kt < 4; ++kt) {
            const int d2b = (kt * 16 + kg * 4) ^ ((col & 7) << 3);
            const uint4 w = *(const uint4*)&Wlds[col][d2b];
            H8 b;
            b.v[0] = u2h(w.x); b.v[1] = u2h(w.y);
            b.v[2] = u2h(w.z); b.v[3] = u2h(w.w);
            C[ct] = __builtin_amdgcn_mfma_f32_16x16x32_f16(
                        A[kt], __builtin_bit_cast(f16x8, b), C[ct], 0, 0, 0);
        }
    }

    // ---- epilogues ----
    if (m == 0) {
        float s0 = 0.f, s1 = 0.f, s2 = 0.f, s3 = 0.f;
#pragma unroll
        for (int ct = 0; ct < 4; ++ct) {
            const int col = (cg * 4 + ct) * 16 + (lane & 15);
            const float b1 = bo1[col];
            const float w2 = Wo2[col];
            s0 = fmaf(fmaxf(C[ct].x + b1, 0.f), w2, s0);
            s1 = fmaf(fmaxf(C[ct].y + b1, 0.f), w2, s1);
            s2 = fmaf(fmaxf(C[ct].z + b1, 0.f), w2, s2);
            s3 = fmaf(fmaxf(C[ct].w + b1, 0.f), w2, s3);
        }
#pragma unroll
        for (int off = 1; off <= 8; off <<= 1) {
            s0 += __shfl_xor(s0, off, 64);
            s1 += __shfl_xor(s1, off, 64);
            s2 += __shfl_xor(s2, off, 64);
            s3 += __shfl_xor(s3, off, 64);
        }
        if ((lane & 15) == 0) {
            const int rbase = rt * 16 + kg * 4;
            org_part[rbase + 0][cg] = s0;
            org_part[rbase + 1][cg] = s1;
            org_part[rbase + 2][cg] = s2;
            org_part[rbase + 3][cg] = s3;
        }
        __syncthreads();
        if (t < 32) {
            const float s = org_part[t][0] + org_part[t][1]
                          + org_part[t][2] + org_part[t][3] + bo2[0];
            organ_out[rb * 32 + t] = sigmoidf_(s);
        }
    } else {
        uint32_t* __restrict__ dst = (m == 1) ? pi_h : pj_h;
        const bool addb = (m == 1);
#pragma unroll
        for (int ct = 0; ct < 4; ++ct) {
            const int col = (cg * 4 + ct) * 16 + (lane & 15);
            const float bv = addb ? be1[col] : 0.f;
            float v0 = C[ct].x + bv, v1 = C[ct].y + bv;
            float v2 = C[ct].z + bv, v3 = C[ct].w + bv;
            const float p0 = __shfl_xor(v0, 1, 64);
            const float p1 = __shfl_xor(v1, 1, 64);
            const float p2 = __shfl_xor(v2, 1, 64);
            const float p3 = __shfl_xor(v3, 1, 64);
            if (!(lane & 1)) {                 // even col: pack (col, col+1)
                const int hp = col >> 1;
                const size_t gr = (size_t)(rb * 32 + rt * 16 + kg * 4);
                dst[(gr + 0) * 128 + hp] = h2u(pkrtz(v0, p0));
                dst[(gr + 1) * 128 + hp] = h2u(pkrtz(v1, p1));
                dst[(gr + 2) * 128 + hp] = h2u(pkrtz(v2, p2));
                dst[(gr + 3) * 128 + hp] = h2u(pkrtz(v3, p3));
            }
        }
    }
}

// ---------------------------------------------------------------------------
// Kernel 2: fused edge head + MASK-SKIP.
// grid 2048 x 256 thr (4 waves, 8 blocks/CU). Same data layout as round 6,
// plus: mask bits for the tile staged as 4-bit rows (mask4_s[jl], bit ii).
// Per (q, ii): readfirstlane'd scalar branch skips the entire pe+relu+dot
// body when mask==0 (~50% of pairs) with zero divergence. Skipped slots keep
// their initialized value and the epilogue multiplies by the staged bit, so
// masked outputs are exact zeros (matches reference).
// ---------------------------------------------------------------------------
__global__ __launch_bounds__(256, 8) void edge_kernel(
    const float* __restrict__ E,      // (N,N,9)
    const int*   __restrict__ mask,   // (N,N)
    const float* __restrict__ We_e,   // (9,256)
    const float* __restrict__ We2,    // (256,1)
    const float* __restrict__ be2,    // (1)
    const uint32_t* __restrict__ pi_h,  // (B*N,128) half2
    const uint32_t* __restrict__ pj_h,  // (B*N,128) half2
    float* __restrict__ edge_out)     // (B,N,N)
{
    __shared__ __align__(16) uint32_t E_s[TI][TJ][12];  // dup'd h2v, 6 KiB
    __shared__ float sums_s[BATCH][TI][33];             // padded, ~1 KiB
    __shared__ uint32_t mask4_s[TJ];                    // 4 mask bits per jl

    const int t    = threadIdx.x;
    const int lane = t & 63;
    const int wave = t >> 6;           // 0..3
    const int bi   = blockIdx.x;
    const int i0   = (bi >> 4) * TI;   // 128 i-blocks
    const int j0   = (bi & 15) * TJ;   // 16 j-blocks

#pragma unroll
    for (int ii = 0; ii < TI; ++ii) {
        const float* src = &E[((size_t)(i0 + ii) * NN + j0) * EDGE_DIM];
        for (int idx = t; idx < TJ * EDGE_DIM; idx += 256) {
            const int jl = idx / 9;
            const int d  = idx - jl * 9;
            const float e = src[idx];
            E_s[ii][jl][d] = h2u(pkrtz(e, e));
        }
    }
    // ---- stage mask bits: mask4_s[jl] bit ii = mask[i0+ii][j0+jl] ----
    if (t < TJ) {
        uint32_t m = 0;
#pragma unroll
        for (int ii = 0; ii < TI; ++ii)
            m |= (mask[(size_t)(i0 + ii) * NN + j0 + t] != 0 ? 1u : 0u) << ii;
        mask4_s[t] = m;
    }

    h2v wee[EDGE_DIM][2];
    const float4* We_e4 = (const float4*)We_e;
#pragma unroll
    for (int d = 0; d < EDGE_DIM; ++d) {
        const float4 w = We_e4[d * 64 + lane];
        wee[d][0] = pkrtz(w.x, w.y);
        wee[d][1] = pkrtz(w.z, w.w);
    }
    h2v w2[2];
    {
        const float4 w = ((const float4*)We2)[lane];
        w2[0] = pkrtz(w.x, w.y);
        w2[1] = pkrtz(w.z, w.w);
    }

    h2v pir[BATCH][TI][2];
#pragma unroll
    for (int b = 0; b < BATCH; ++b)
#pragma unroll
        for (int ii = 0; ii < TI; ++ii) {
            const uint2 u = ((const uint2*)&pi_h[(size_t)(b * NN + i0 + ii) * 128])[lane];
            pir[b][ii][0] = u2h(u.x);
            pir[b][ii][1] = u2h(u.y);
        }

    __syncthreads();

    uint2 pjp[BATCH];
    {
        const int j = j0 + wave * 8;
        pjp[0] = ((const uint2*)&pj_h[(size_t)(0 * NN + j) * 128])[lane];
        pjp[1] = ((const uint2*)&pj_h[(size_t)(1 * NN + j) * 128])[lane];
    }

    float vals[8] = {0.f, 0.f, 0.f, 0.f, 0.f, 0.f, 0.f, 0.f};

#pragma unroll
    for (int q = 0; q < 8; ++q) {
        const int jl = wave * 8 + q;

        h2v pjr[BATCH][2];
        pjr[0][0] = u2h(pjp[0].x); pjr[0][1] = u2h(pjp[0].y);
        pjr[1][0] = u2h(pjp[1].x); pjr[1][1] = u2h(pjp[1].y);

        if (q < 7) {
            const int j = j0 + jl + 1;
            pjp[0] = ((const uint2*)&pj_h[(size_t)(0 * NN + j) * 128])[lane];
            pjp[1] = ((const uint2*)&pj_h[(size_t)(1 * NN + j) * 128])[lane];
        }

        // scalar mask bits for this jl (uniform across the wave)
        const int m4 = __builtin_amdgcn_readfirstlane((int)mask4_s[jl]);

#pragma unroll
        for (int ii = 0; ii < TI; ++ii) {
            if (m4 & (1 << ii)) {
                const uint32_t* erow = &E_s[ii][jl][0];
                const uint4 ua = *(const uint4*)(erow);
                const uint4 ub = *(const uint4*)(erow + 4);
                const uint32_t uc = erow[8];

                h2v pe0, pe1;
                {
                    const h2v e0 = u2h(ua.x), e1 = u2h(ua.y), e2 = u2h(ua.z), e3 = u2h(ua.w);
                    const h2v e4 = u2h(ub.x), e5 = u2h(ub.y), e6 = u2h(ub.z), e7 = u2h(ub.w);
                    const h2v e8 = u2h(uc);
                    pe0 = e0 * wee[0][0];            pe1 = e0 * wee[0][1];
                    pe0 = pe0 + e1 * wee[1][0];      pe1 = pe1 + e1 * wee[1][1];
                    pe0 = pe0 + e2 * wee[2][0];      pe1 = pe1 + e2 * wee[2][1];
                    pe0 = pe0 + e3 * wee[3][0];      pe1 = pe1 + e3 * wee[3][1];
                    pe0 = pe0 + e4 * wee[4][0];      pe1 = pe1 + e4 * wee[4][1];
                    pe0 = pe0 + e5 * wee[5][0];      pe1 = pe1 + e5 * wee[5][1];
                    pe0 = pe0 + e6 * wee[6][0];      pe1 = pe1 + e6 * wee[6][1];
                    pe0 = pe0 + e7 * wee[7][0];      pe1 = pe1 + e7 * wee[7][1];
                    pe0 = pe0 + e8 * wee[8][0];      pe1 = pe1 + e8 * wee[8][1];
                }

#pragma unroll
                for (int b = 0; b < BATCH; ++b) {
                    h2v v0 = relu2(pir[b][ii][0] + pjr[b][0] + pe0);
                    h2v v1 = relu2(pir[b][ii][1] + pjr[b][1] + pe1);
                    vals[2 * ii + b] = fdot2(v1, w2[1], fdot2(v0, w2[0], 0.f));
                }
            }
        }

        float a0, a1, a2, a3;
        {
            const bool b0 = lane & 1;
            float k0 = b0 ? vals[1] : vals[0], s0 = b0 ? vals[0] : vals[1];
            float k1 = b0 ? vals[3] : vals[2], s1 = b0 ? vals[2] : vals[3];
            float k2 = b0 ? vals[5] : vals[4], s2 = b0 ? vals[4] : vals[5];
            float k3 = b0 ? vals[7] : vals[6], s3 = b0 ? vals[6] : vals[7];
            a0 = k0 + __shfl_xor(s0, 1, 64);
            a1 = k1 + __shfl_xor(s1, 1, 64);
            a2 = k2 + __shfl_xor(s2, 1, 64);
            a3 = k3 + __shfl_xor(s3, 1, 64);
        }
        {
            const bool b1 = (lane >> 1) & 1;
            float k0 = b1 ? a1 : a0, s0 = b1 ? a0 : a1;
            float k1 = b1 ? a3 : a2, s1 = b1 ? a2 : a3;
            a0 = k0 + __shfl_xor(s0, 2, 64);
            a1 = k1 + __shfl_xor(s1, 2, 64);
        }
        {
            const bool b2 = (lane >> 2) & 1;
            float k = b2 ? a1 : a0, s = b2 ? a0 : a1;
            a0 = k + __shfl_xor(s, 4, 64);
        }
        a0 += __shfl_xor(a0, 8, 64);
        a0 += __shfl_xor(a0, 16, 64);
        a0 += __shfl_xor(a0, 32, 64);

        if (lane < 8) sums_s[lane & 1][lane >> 1][jl] = a0;
    }
    __syncthreads();

    {
        const int b   = t >> 7;
        const int rem = t & 127;
        const int ii  = rem >> 5;
        const int jl  = rem & 31;
        const int i = i0 + ii, j = j0 + jl;
        const float mv = (float)((mask4_s[jl] >> ii) & 1u);
        const float s = sums_s[b][ii][jl] + be2[0];
        float p = sigmoidf_(s) * mv;
        edge_out[((size_t)b * NN + i) * NN + j] = p;
    }
}

extern "C" void kernel_launch(void* const* d_in, const int* in_sizes, int n_in,
                              void* d_out, int out_size, void* d_ws, size_t ws_size,
                              hipStream_t stream) {
    const float* z    = (const float*)d_in[0];   // (B,N,128)
    const float* E    = (const float*)d_in[1];   // (N,N,9)
    const int*   mask = (const int*)  d_in[2];   // (N,N)
    const float* Wo1  = (const float*)d_in[3];
    const float* bo1  = (const float*)d_in[4];
    const float* Wo2  = (const float*)d_in[5];
    const float* bo2  = (const float*)d_in[6];
    const float* We_i = (const float*)d_in[7];
    const float* We_j = (const float*)d_in[8];
    const float* We_e = (const float*)d_in[9];
    const float* be1  = (const float*)d_in[10];
    const float* We2  = (const float*)d_in[11];
    const float* be2  = (const float*)d_in[12];

    float* out_organ = (float*)d_out;                 // (B,N) = 1024
    float* out_edge  = out_organ + BATCH * NN;        // (B,N,N)

    uint32_t* pi_h = (uint32_t*)d_ws;                        // (B*N,128) half2
    uint32_t* pj_h = pi_h + (size_t)BATCH * NN * (HIDDEN/2); // (B*N,128) half2

    hipLaunchKernelGGL(node_mfma_kernel,
                       dim3(32, 3), dim3(512), 0, stream,
                       z, Wo1, bo1, Wo2, bo2, We_i, We_j, be1,
                       out_organ, pi_h, pj_h);

    hipLaunchKernelGGL(edge_kernel,
                       dim3((NN / TI) * (NN / TJ)), dim3(256), 0, stream,
                       E, mask, We_e, We2, be2, pi_h, pj_h, out_edge);
}

// Round 9
// 46.302 us; speedup vs baseline: 1.0907x; 1.0907x over previous
//
#include <hip/hip_runtime.h>
#include <math.h>
#include <stdint.h>

#define D_MODEL 128
#define EDGE_DIM 9
#define HIDDEN 256
#define BATCH 2
#define NN 512

#define TI 4     // i-tile in kernel 2
#define TJ 32    // j-tile in kernel 2

typedef _Float16 h2v    __attribute__((ext_vector_type(2)));
typedef __fp16   fp16x2 __attribute__((ext_vector_type(2)));
typedef _Float16 f16x8  __attribute__((ext_vector_type(8)));
typedef float    f32x4  __attribute__((ext_vector_type(4)));

struct H8 { h2v v[4]; };   // 16B = one MFMA A/B fragment

__device__ __forceinline__ uint32_t h2u(h2v v) { return __builtin_bit_cast(uint32_t, v); }
__device__ __forceinline__ h2v u2h(uint32_t u) { return __builtin_bit_cast(h2v, u); }
__device__ __forceinline__ h2v pkrtz(float a, float b) {
    return __builtin_bit_cast(h2v, __builtin_amdgcn_cvt_pkrtz(a, b));
}
__device__ __forceinline__ h2v relu2(h2v v) {
    h2v z = {(_Float16)0.0f, (_Float16)0.0f};
    return __builtin_elementwise_max(v, z);
}
__device__ __forceinline__ float fdot2(h2v a, h2v b, float c) {
    return __builtin_amdgcn_fdot2(__builtin_bit_cast(fp16x2, a),
                                  __builtin_bit_cast(fp16x2, b), c, false);
}
__device__ __forceinline__ float sigmoidf_(float x) { return 1.f / (1.f + expf(-x)); }

// ---------------------------------------------------------------------------
// Kernel 1 (MFMA): C = z @ W for one of {Wo1, We_i, We_j} per block.y.
// (Unchanged from round 7.)
// ---------------------------------------------------------------------------
__global__ __launch_bounds__(512) void node_mfma_kernel(
    const float* __restrict__ z,      // (B*N, 128)
    const float* __restrict__ Wo1,    // (128,256)
    const float* __restrict__ bo1,    // (256)
    const float* __restrict__ Wo2,    // (256,1)
    const float* __restrict__ bo2,    // (1)
    const float* __restrict__ We_i,   // (128,256)
    const float* __restrict__ We_j,   // (128,256)
    const float* __restrict__ be1,    // (256)
    float* __restrict__ organ_out,    // (B*N)
    uint32_t* __restrict__ pi_h,      // (B*N,128) half2, includes +be1
    uint32_t* __restrict__ pj_h)      // (B*N,128) half2
{
    __shared__ uint32_t Wlds[256][68];     // ~69.6 KiB, f16-pair, [h][d2^swz]
    __shared__ float org_part[32][4];

    const int t    = threadIdx.x;
    const int lane = t & 63;
    const int wave = t >> 6;
    const int rb   = blockIdx.x;           // row-block: rows 32*rb..32*rb+31
    const int m    = blockIdx.y;           // 0 = Wo1/organ, 1 = We_i/pi, 2 = We_j/pj

    const float* __restrict__ W = (m == 0) ? Wo1 : (m == 1) ? We_i : We_j;

    // ---- stage W -> LDS f16, transposed, swizzled ----
    for (int idx = t; idx < 64 * 256; idx += 512) {
        const int d2 = idx >> 8;           // 0..63 (d-pair)
        const int h  = idx & 255;          // coalesced over h
        const float wlo = W[(2 * d2) * 256 + h];
        const float whi = W[(2 * d2 + 1) * 256 + h];
        Wlds[h][d2 ^ ((h & 7) << 3)] = h2u(pkrtz(wlo, whi));
    }

    // ---- A-frags straight from global ----
    const int rt = wave & 1;               // row-tile
    const int cg = wave >> 1;              // col-group (4 tiles of 16)
    const int kg = lane >> 4;              // k-subgroup
    const int row = rb * 32 + rt * 16 + (lane & 15);

    f16x8 A[4];
#pragma unroll
    for (int kt = 0; kt < 4; ++kt) {
        const float4 za = *(const float4*)&z[(size_t)row * 128 + kt * 32 + kg * 8];
        const float4 zb = *(const float4*)&z[(size_t)row * 128 + kt * 32 + kg * 8 + 4];
        H8 a;
        a.v[0] = pkrtz(za.x, za.y); a.v[1] = pkrtz(za.z, za.w);
        a.v[2] = pkrtz(zb.x, zb.y); a.v[3] = pkrtz(zb.z, zb.w);
        A[kt] = __builtin_bit_cast(f16x8, a);
    }

    __syncthreads();

    // ---- MFMA main: 4 col-tiles x 4 k-tiles ----
    f32x4 C[4];
#pragma unroll
    for (int ct = 0; ct < 4; ++ct) {
        const int col = (cg * 4 + ct) * 16 + (lane & 15);
        C[ct] = (f32x4){0.f, 0.f, 0.f, 0.f};
#pragma unroll
        for (int kt = 0; kt < 4; ++kt) {
            const int d2b = (kt * 16 + kg * 4) ^ ((col & 7) << 3);
            const uint4 w = *(const uint4*)&Wlds[col][d2b];
            H8 b;
            b.v[0] = u2h(w.x); b.v[1] = u2h(w.y);
            b.v[2] = u2h(w.z); b.v[3] = u2h(w.w);
            C[ct] = __builtin_amdgcn_mfma_f32_16x16x32_f16(
                        A[kt], __builtin_bit_cast(f16x8, b), C[ct], 0, 0, 0);
        }
    }

    // ---- epilogues ----
    if (m == 0) {
        float s0 = 0.f, s1 = 0.f, s2 = 0.f, s3 = 0.f;
#pragma unroll
        for (int ct = 0; ct < 4; ++ct) {
            const int col = (cg * 4 + ct) * 16 + (lane & 15);
            const float b1 = bo1[col];
            const float w2 = Wo2[col];
            s0 = fmaf(fmaxf(C[ct].x + b1, 0.f), w2, s0);
            s1 = fmaf(fmaxf(C[ct].y + b1, 0.f), w2, s1);
            s2 = fmaf(fmaxf(C[ct].z + b1, 0.f), w2, s2);
            s3 = fmaf(fmaxf(C[ct].w + b1, 0.f), w2, s3);
        }
#pragma unroll
        for (int off = 1; off <= 8; off <<= 1) {
            s0 += __shfl_xor(s0, off, 64);
            s1 += __shfl_xor(s1, off, 64);
            s2 += __shfl_xor(s2, off, 64);
            s3 += __shfl_xor(s3, off, 64);
        }
        if ((lane & 15) == 0) {
            const int rbase = rt * 16 + kg * 4;
            org_part[rbase + 0][cg] = s0;
            org_part[rbase + 1][cg] = s1;
            org_part[rbase + 2][cg] = s2;
            org_part[rbase + 3][cg] = s3;
        }
        __syncthreads();
        if (t < 32) {
            const float s = org_part[t][0] + org_part[t][1]
                          + org_part[t][2] + org_part[t][3] + bo2[0];
            organ_out[rb * 32 + t] = sigmoidf_(s);
        }
    } else {
        uint32_t* __restrict__ dst = (m == 1) ? pi_h : pj_h;
        const bool addb = (m == 1);
#pragma unroll
        for (int ct = 0; ct < 4; ++ct) {
            const int col = (cg * 4 + ct) * 16 + (lane & 15);
            const float bv = addb ? be1[col] : 0.f;
            float v0 = C[ct].x + bv, v1 = C[ct].y + bv;
            float v2 = C[ct].z + bv, v3 = C[ct].w + bv;
            const float p0 = __shfl_xor(v0, 1, 64);
            const float p1 = __shfl_xor(v1, 1, 64);
            const float p2 = __shfl_xor(v2, 1, 64);
            const float p3 = __shfl_xor(v3, 1, 64);
            if (!(lane & 1)) {                 // even col: pack (col, col+1)
                const int hp = col >> 1;
                const size_t gr = (size_t)(rb * 32 + rt * 16 + kg * 4);
                dst[(gr + 0) * 128 + hp] = h2u(pkrtz(v0, p0));
                dst[(gr + 1) * 128 + hp] = h2u(pkrtz(v1, p1));
                dst[(gr + 2) * 128 + hp] = h2u(pkrtz(v2, p2));
                dst[(gr + 3) * 128 + hp] = h2u(pkrtz(v3, p3));
            }
        }
    }
}

// ---------------------------------------------------------------------------
// Kernel 2: fused edge head + mask-skip, SPILL-FIXED.
// Identical to round 8 except vals[] is declared INSIDE the q loop with
// unconditional zero-init (no cross-iteration liveness -> stays in VGPRs;
// round 8's hoisted/conditionally-written array went to scratch: VGPR 56->32,
// WRITE_SIZE 2->35 MB). Skipped (i,j) slots stay exactly 0 and the epilogue
// multiplies by the staged mask bit.
// ---------------------------------------------------------------------------
__global__ __launch_bounds__(256, 8) void edge_kernel(
    const float* __restrict__ E,      // (N,N,9)
    const int*   __restrict__ mask,   // (N,N)
    const float* __restrict__ We_e,   // (9,256)
    const float* __restrict__ We2,    // (256,1)
    const float* __restrict__ be2,    // (1)
    const uint32_t* __restrict__ pi_h,  // (B*N,128) half2
    const uint32_t* __restrict__ pj_h,  // (B*N,128) half2
    float* __restrict__ edge_out)     // (B,N,N)
{
    __shared__ __align__(16) uint32_t E_s[TI][TJ][12];  // dup'd h2v, 6 KiB
    __shared__ float sums_s[BATCH][TI][33];             // padded, ~1 KiB
    __shared__ uint32_t mask4_s[TJ];                    // 4 mask bits per jl

    const int t    = threadIdx.x;
    const int lane = t & 63;
    const int wave = t >> 6;           // 0..3
    const int bi   = blockIdx.x;
    const int i0   = (bi >> 4) * TI;   // 128 i-blocks
    const int j0   = (bi & 15) * TJ;   // 16 j-blocks

#pragma unroll
    for (int ii = 0; ii < TI; ++ii) {
        const float* src = &E[((size_t)(i0 + ii) * NN + j0) * EDGE_DIM];
        for (int idx = t; idx < TJ * EDGE_DIM; idx += 256) {
            const int jl = idx / 9;
            const int d  = idx - jl * 9;
            const float e = src[idx];
            E_s[ii][jl][d] = h2u(pkrtz(e, e));
        }
    }
    // ---- stage mask bits: mask4_s[jl] bit ii = mask[i0+ii][j0+jl] ----
    if (t < TJ) {
        uint32_t m = 0;
#pragma unroll
        for (int ii = 0; ii < TI; ++ii)
            m |= (mask[(size_t)(i0 + ii) * NN + j0 + t] != 0 ? 1u : 0u) << ii;
        mask4_s[t] = m;
    }

    h2v wee[EDGE_DIM][2];
    const float4* We_e4 = (const float4*)We_e;
#pragma unroll
    for (int d = 0; d < EDGE_DIM; ++d) {
        const float4 w = We_e4[d * 64 + lane];
        wee[d][0] = pkrtz(w.x, w.y);
        wee[d][1] = pkrtz(w.z, w.w);
    }
    h2v w2[2];
    {
        const float4 w = ((const float4*)We2)[lane];
        w2[0] = pkrtz(w.x, w.y);
        w2[1] = pkrtz(w.z, w.w);
    }

    h2v pir[BATCH][TI][2];
#pragma unroll
    for (int b = 0; b < BATCH; ++b)
#pragma unroll
        for (int ii = 0; ii < TI; ++ii) {
            const uint2 u = ((const uint2*)&pi_h[(size_t)(b * NN + i0 + ii) * 128])[lane];
            pir[b][ii][0] = u2h(u.x);
            pir[b][ii][1] = u2h(u.y);
        }

    __syncthreads();

    uint2 pjp[BATCH];
    {
        const int j = j0 + wave * 8;
        pjp[0] = ((const uint2*)&pj_h[(size_t)(0 * NN + j) * 128])[lane];
        pjp[1] = ((const uint2*)&pj_h[(size_t)(1 * NN + j) * 128])[lane];
    }

#pragma unroll
    for (int q = 0; q < 8; ++q) {
        const int jl = wave * 8 + q;

        h2v pjr[BATCH][2];
        pjr[0][0] = u2h(pjp[0].x); pjr[0][1] = u2h(pjp[0].y);
        pjr[1][0] = u2h(pjp[1].x); pjr[1][1] = u2h(pjp[1].y);

        if (q < 7) {
            const int j = j0 + jl + 1;
            pjp[0] = ((const uint2*)&pj_h[(size_t)(0 * NN + j) * 128])[lane];
            pjp[1] = ((const uint2*)&pj_h[(size_t)(1 * NN + j) * 128])[lane];
        }

        // scalar mask bits for this jl (uniform across the wave)
        const int m4 = __builtin_amdgcn_readfirstlane((int)mask4_s[jl]);

        // fresh per-q accumulators: unconditional init -> stays in VGPRs
        float vals[8] = {0.f, 0.f, 0.f, 0.f, 0.f, 0.f, 0.f, 0.f};

#pragma unroll
        for (int ii = 0; ii < TI; ++ii) {
            if (m4 & (1 << ii)) {
                const uint32_t* erow = &E_s[ii][jl][0];
                const uint4 ua = *(const uint4*)(erow);
                const uint4 ub = *(const uint4*)(erow + 4);
                const uint32_t uc = erow[8];

                h2v pe0, pe1;
                {
                    const h2v e0 = u2h(ua.x), e1 = u2h(ua.y), e2 = u2h(ua.z), e3 = u2h(ua.w);
                    const h2v e4 = u2h(ub.x), e5 = u2h(ub.y), e6 = u2h(ub.z), e7 = u2h(ub.w);
                    const h2v e8 = u2h(uc);
                    pe0 = e0 * wee[0][0];            pe1 = e0 * wee[0][1];
                    pe0 = pe0 + e1 * wee[1][0];      pe1 = pe1 + e1 * wee[1][1];
                    pe0 = pe0 + e2 * wee[2][0];      pe1 = pe1 + e2 * wee[2][1];
                    pe0 = pe0 + e3 * wee[3][0];      pe1 = pe1 + e3 * wee[3][1];
                    pe0 = pe0 + e4 * wee[4][0];      pe1 = pe1 + e4 * wee[4][1];
                    pe0 = pe0 + e5 * wee[5][0];      pe1 = pe1 + e5 * wee[5][1];
                    pe0 = pe0 + e6 * wee[6][0];      pe1 = pe1 + e6 * wee[6][1];
                    pe0 = pe0 + e7 * wee[7][0];      pe1 = pe1 + e7 * wee[7][1];
                    pe0 = pe0 + e8 * wee[8][0];      pe1 = pe1 + e8 * wee[8][1];
                }

#pragma unroll
                for (int b = 0; b < BATCH; ++b) {
                    h2v v0 = relu2(pir[b][ii][0] + pjr[b][0] + pe0);
                    h2v v1 = relu2(pir[b][ii][1] + pjr[b][1] + pe1);
                    vals[2 * ii + b] = fdot2(v1, w2[1], fdot2(v0, w2[0], 0.f));
                }
            }
        }

        float a0, a1, a2, a3;
        {
            const bool b0 = lane & 1;
            float k0 = b0 ? vals[1] : vals[0], s0 = b0 ? vals[0] : vals[1];
            float k1 = b0 ? vals[3] : vals[2], s1 = b0 ? vals[2] : vals[3];
            float k2 = b0 ? vals[5] : vals[4], s2 = b0 ? vals[4] : vals[5];
            float k3 = b0 ? vals[7] : vals[6], s3 = b0 ? vals[6] : vals[7];
            a0 = k0 + __shfl_xor(s0, 1, 64);
            a1 = k1 + __shfl_xor(s1, 1, 64);
            a2 = k2 + __shfl_xor(s2, 1, 64);
            a3 = k3 + __shfl_xor(s3, 1, 64);
        }
        {
            const bool b1 = (lane >> 1) & 1;
            float k0 = b1 ? a1 : a0, s0 = b1 ? a0 : a1;
            float k1 = b1 ? a3 : a2, s1 = b1 ? a2 : a3;
            a0 = k0 + __shfl_xor(s0, 2, 64);
            a1 = k1 + __shfl_xor(s1, 2, 64);
        }
        {
            const bool b2 = (lane >> 2) & 1;
            float k = b2 ? a1 : a0, s = b2 ? a0 : a1;
            a0 = k + __shfl_xor(s, 4, 64);
        }
        a0 += __shfl_xor(a0, 8, 64);
        a0 += __shfl_xor(a0, 16, 64);
        a0 += __shfl_xor(a0, 32, 64);

        if (lane < 8) sums_s[lane & 1][lane >> 1][jl] = a0;
    }
    __syncthreads();

    {
        const int b   = t >> 7;
        const int rem = t & 127;
        const int ii  = rem >> 5;
        const int jl  = rem & 31;
        const int i = i0 + ii, j = j0 + jl;
        const float mv = (float)((mask4_s[jl] >> ii) & 1u);
        const float s = sums_s[b][ii][jl] + be2[0];
        float p = sigmoidf_(s) * mv;
        edge_out[((size_t)b * NN + i) * NN + j] = p;
    }
}

extern "C" void kernel_launch(void* const* d_in, const int* in_sizes, int n_in,
                              void* d_out, int out_size, void* d_ws, size_t ws_size,
                              hipStream_t stream) {
    const float* z    = (const float*)d_in[0];   // (B,N,128)
    const float* E    = (const float*)d_in[1];   // (N,N,9)
    const int*   mask = (const int*)  d_in[2];   // (N,N)
    const float* Wo1  = (const float*)d_in[3];
    const float* bo1  = (const float*)d_in[4];
    const float* Wo2  = (const float*)d_in[5];
    const float* bo2  = (const float*)d_in[6];
    const float* We_i = (const float*)d_in[7];
    const float* We_j = (const float*)d_in[8];
    const float* We_e = (const float*)d_in[9];
    const float* be1  = (const float*)d_in[10];
    const float* We2  = (const float*)d_in[11];
    const float* be2  = (const float*)d_in[12];

    float* out_organ = (float*)d_out;                 // (B,N) = 1024
    float* out_edge  = out_organ + BATCH * NN;        // (B,N,N)

    uint32_t* pi_h = (uint32_t*)d_ws;                        // (B*N,128) half2
    uint32_t* pj_h = pi_h + (size_t)BATCH * NN * (HIDDEN/2); // (B*N,128) half2

    hipLaunchKernelGGL(node_mfma_kernel,
                       dim3(32, 3), dim3(512), 0, stream,
                       z, Wo1, bo1, Wo2, bo2, We_i, We_j, be1,
                       out_organ, pi_h, pj_h);

    hipLaunchKernelGGL(edge_kernel,
                       dim3((NN / TI) * (NN / TJ)), dim3(256), 0, stream,
                       E, mask, We_e, We2, be2, pi_h, pj_h, out_edge);
}

// Round 10
// 43.641 us; speedup vs baseline: 1.1572x; 1.0610x over previous
//
#include <hip/hip_runtime.h>
#include <math.h>
#include <stdint.h>

#define D_MODEL 128
#define EDGE_DIM 9
#define HIDDEN 256
#define BATCH 2
#define NN 512

#define TI 4     // i-tile in kernel 2
#define TJ 32    // j-tile in kernel 2

typedef _Float16 h2v    __attribute__((ext_vector_type(2)));
typedef __fp16   fp16x2 __attribute__((ext_vector_type(2)));
typedef _Float16 f16x8  __attribute__((ext_vector_type(8)));
typedef float    f32x4  __attribute__((ext_vector_type(4)));

struct H8 { h2v v[4]; };   // 16B = one MFMA A/B fragment

__device__ __forceinline__ uint32_t h2u(h2v v) { return __builtin_bit_cast(uint32_t, v); }
__device__ __forceinline__ h2v u2h(uint32_t u) { return __builtin_bit_cast(h2v, u); }
__device__ __forceinline__ h2v pkrtz(float a, float b) {
    return __builtin_bit_cast(h2v, __builtin_amdgcn_cvt_pkrtz(a, b));
}
__device__ __forceinline__ h2v relu2(h2v v) {
    h2v z = {(_Float16)0.0f, (_Float16)0.0f};
    return __builtin_elementwise_max(v, z);
}
__device__ __forceinline__ float fdot2(h2v a, h2v b, float c) {
    return __builtin_amdgcn_fdot2(__builtin_bit_cast(fp16x2, a),
                                  __builtin_bit_cast(fp16x2, b), c, false);
}
__device__ __forceinline__ float sigmoidf_(float x) { return 1.f / (1.f + expf(-x)); }

// ---------------------------------------------------------------------------
// Kernel 1 (MFMA): C = z @ W for one of {Wo1, We_i, We_j} per block.y.
// (Unchanged from round 7.)
// ---------------------------------------------------------------------------
__global__ __launch_bounds__(512) void node_mfma_kernel(
    const float* __restrict__ z,      // (B*N, 128)
    const float* __restrict__ Wo1,    // (128,256)
    const float* __restrict__ bo1,    // (256)
    const float* __restrict__ Wo2,    // (256,1)
    const float* __restrict__ bo2,    // (1)
    const float* __restrict__ We_i,   // (128,256)
    const float* __restrict__ We_j,   // (128,256)
    const float* __restrict__ be1,    // (256)
    float* __restrict__ organ_out,    // (B*N)
    uint32_t* __restrict__ pi_h,      // (B*N,128) half2, includes +be1
    uint32_t* __restrict__ pj_h)      // (B*N,128) half2
{
    __shared__ uint32_t Wlds[256][68];     // ~69.6 KiB, f16-pair, [h][d2^swz]
    __shared__ float org_part[32][4];

    const int t    = threadIdx.x;
    const int lane = t & 63;
    const int wave = t >> 6;
    const int rb   = blockIdx.x;           // row-block: rows 32*rb..32*rb+31
    const int m    = blockIdx.y;           // 0 = Wo1/organ, 1 = We_i/pi, 2 = We_j/pj

    const float* __restrict__ W = (m == 0) ? Wo1 : (m == 1) ? We_i : We_j;

    // ---- stage W -> LDS f16, transposed, swizzled ----
    for (int idx = t; idx < 64 * 256; idx += 512) {
        const int d2 = idx >> 8;           // 0..63 (d-pair)
        const int h  = idx & 255;          // coalesced over h
        const float wlo = W[(2 * d2) * 256 + h];
        const float whi = W[(2 * d2 + 1) * 256 + h];
        Wlds[h][d2 ^ ((h & 7) << 3)] = h2u(pkrtz(wlo, whi));
    }

    // ---- A-frags straight from global ----
    const int rt = wave & 1;               // row-tile
    const int cg = wave >> 1;              // col-group (4 tiles of 16)
    const int kg = lane >> 4;              // k-subgroup
    const int row = rb * 32 + rt * 16 + (lane & 15);

    f16x8 A[4];
#pragma unroll
    for (int kt = 0; kt < 4; ++kt) {
        const float4 za = *(const float4*)&z[(size_t)row * 128 + kt * 32 + kg * 8];
        const float4 zb = *(const float4*)&z[(size_t)row * 128 + kt * 32 + kg * 8 + 4];
        H8 a;
        a.v[0] = pkrtz(za.x, za.y); a.v[1] = pkrtz(za.z, za.w);
        a.v[2] = pkrtz(zb.x, zb.y); a.v[3] = pkrtz(zb.z, zb.w);
        A[kt] = __builtin_bit_cast(f16x8, a);
    }

    __syncthreads();

    // ---- MFMA main: 4 col-tiles x 4 k-tiles ----
    f32x4 C[4];
#pragma unroll
    for (int ct = 0; ct < 4; ++ct) {
        const int col = (cg * 4 + ct) * 16 + (lane & 15);
        C[ct] = (f32x4){0.f, 0.f, 0.f, 0.f};
#pragma unroll
        for (int kt = 0; kt < 4; ++kt) {
            const int d2b = (kt * 16 + kg * 4) ^ ((col & 7) << 3);
            const uint4 w = *(const uint4*)&Wlds[col][d2b];
            H8 b;
            b.v[0] = u2h(w.x); b.v[1] = u2h(w.y);
            b.v[2] = u2h(w.z); b.v[3] = u2h(w.w);
            C[ct] = __builtin_amdgcn_mfma_f32_16x16x32_f16(
                        A[kt], __builtin_bit_cast(f16x8, b), C[ct], 0, 0, 0);
        }
    }

    // ---- epilogues ----
    if (m == 0) {
        float s0 = 0.f, s1 = 0.f, s2 = 0.f, s3 = 0.f;
#pragma unroll
        for (int ct = 0; ct < 4; ++ct) {
            const int col = (cg * 4 + ct) * 16 + (lane & 15);
            const float b1 = bo1[col];
            const float w2 = Wo2[col];
            s0 = fmaf(fmaxf(C[ct].x + b1, 0.f), w2, s0);
            s1 = fmaf(fmaxf(C[ct].y + b1, 0.f), w2, s1);
            s2 = fmaf(fmaxf(C[ct].z + b1, 0.f), w2, s2);
            s3 = fmaf(fmaxf(C[ct].w + b1, 0.f), w2, s3);
        }
#pragma unroll
        for (int off = 1; off <= 8; off <<= 1) {
            s0 += __shfl_xor(s0, off, 64);
            s1 += __shfl_xor(s1, off, 64);
            s2 += __shfl_xor(s2, off, 64);
            s3 += __shfl_xor(s3, off, 64);
        }
        if ((lane & 15) == 0) {
            const int rbase = rt * 16 + kg * 4;
            org_part[rbase + 0][cg] = s0;
            org_part[rbase + 1][cg] = s1;
            org_part[rbase + 2][cg] = s2;
            org_part[rbase + 3][cg] = s3;
        }
        __syncthreads();
        if (t < 32) {
            const float s = org_part[t][0] + org_part[t][1]
                          + org_part[t][2] + org_part[t][3] + bo2[0];
            organ_out[rb * 32 + t] = sigmoidf_(s);
        }
    } else {
        uint32_t* __restrict__ dst = (m == 1) ? pi_h : pj_h;
        const bool addb = (m == 1);
#pragma unroll
        for (int ct = 0; ct < 4; ++ct) {
            const int col = (cg * 4 + ct) * 16 + (lane & 15);
            const float bv = addb ? be1[col] : 0.f;
            float v0 = C[ct].x + bv, v1 = C[ct].y + bv;
            float v2 = C[ct].z + bv, v3 = C[ct].w + bv;
            const float p0 = __shfl_xor(v0, 1, 64);
            const float p1 = __shfl_xor(v1, 1, 64);
            const float p2 = __shfl_xor(v2, 1, 64);
            const float p3 = __shfl_xor(v3, 1, 64);
            if (!(lane & 1)) {                 // even col: pack (col, col+1)
                const int hp = col >> 1;
                const size_t gr = (size_t)(rb * 32 + rt * 16 + kg * 4);
                dst[(gr + 0) * 128 + hp] = h2u(pkrtz(v0, p0));
                dst[(gr + 1) * 128 + hp] = h2u(pkrtz(v1, p1));
                dst[(gr + 2) * 128 + hp] = h2u(pkrtz(v2, p2));
                dst[(gr + 3) * 128 + hp] = h2u(pkrtz(v3, p3));
            }
        }
    }
}

// ---------------------------------------------------------------------------
// Kernel 2: fused edge head + mask-skip v2.
// Fixes vs round 9:
//  (1) mask bits hoisted into ONE SGPR per wave (mw, 32 bits = 8q x 4ii)
//      BEFORE the q-loop -> per-(q,ii) skip is s_bitcmp+s_cbranch, no LDS
//      read, no waitcnt in the loop.
//  (2) reduce truncated to the 3 select+exchange levels; each lane writes its
//      subgroup partial to part_s[wave][q][o][sub] (2-way bank alias = free);
//      butterflies (3 serial shfl levels/q) deleted. Parallel epilogue: each
//      of 256 threads sums 8 consecutive floats (2x b128) for one output.
// ---------------------------------------------------------------------------
__global__ __launch_bounds__(256, 8) void edge_kernel(
    const float* __restrict__ E,      // (N,N,9)
    const int*   __restrict__ mask,   // (N,N)
    const float* __restrict__ We_e,   // (9,256)
    const float* __restrict__ We2,    // (256,1)
    const float* __restrict__ be2,    // (1)
    const uint32_t* __restrict__ pi_h,  // (B*N,128) half2
    const uint32_t* __restrict__ pj_h,  // (B*N,128) half2
    float* __restrict__ edge_out)     // (B,N,N)
{
    __shared__ __align__(16) uint32_t E_s[TI][TJ][12];  // dup'd h2v, 6 KiB
    __shared__ __align__(16) float part_s[4][8][8][8];  // [wave][q][o][sub], 8 KiB
    __shared__ uint32_t mask4_s[TJ];                    // 4 mask bits per jl

    const int t    = threadIdx.x;
    const int lane = t & 63;
    const int wave = t >> 6;           // 0..3
    const int bi   = blockIdx.x;
    const int i0   = (bi >> 4) * TI;   // 128 i-blocks
    const int j0   = (bi & 15) * TJ;   // 16 j-blocks

#pragma unroll
    for (int ii = 0; ii < TI; ++ii) {
        const float* src = &E[((size_t)(i0 + ii) * NN + j0) * EDGE_DIM];
        for (int idx = t; idx < TJ * EDGE_DIM; idx += 256) {
            const int jl = idx / 9;
            const int d  = idx - jl * 9;
            const float e = src[idx];
            E_s[ii][jl][d] = h2u(pkrtz(e, e));
        }
    }
    // ---- stage mask bits: mask4_s[jl] bit ii = mask[i0+ii][j0+jl] ----
    if (t < TJ) {
        uint32_t m = 0;
#pragma unroll
        for (int ii = 0; ii < TI; ++ii)
            m |= (mask[(size_t)(i0 + ii) * NN + j0 + t] != 0 ? 1u : 0u) << ii;
        mask4_s[t] = m;
    }

    h2v wee[EDGE_DIM][2];
    const float4* We_e4 = (const float4*)We_e;
#pragma unroll
    for (int d = 0; d < EDGE_DIM; ++d) {
        const float4 w = We_e4[d * 64 + lane];
        wee[d][0] = pkrtz(w.x, w.y);
        wee[d][1] = pkrtz(w.z, w.w);
    }
    h2v w2[2];
    {
        const float4 w = ((const float4*)We2)[lane];
        w2[0] = pkrtz(w.x, w.y);
        w2[1] = pkrtz(w.z, w.w);
    }

    h2v pir[BATCH][TI][2];
#pragma unroll
    for (int b = 0; b < BATCH; ++b)
#pragma unroll
        for (int ii = 0; ii < TI; ++ii) {
            const uint2 u = ((const uint2*)&pi_h[(size_t)(b * NN + i0 + ii) * 128])[lane];
            pir[b][ii][0] = u2h(u.x);
            pir[b][ii][1] = u2h(u.y);
        }

    __syncthreads();

    // ---- hoist this wave's 32 mask bits into one scalar register ----
    uint32_t mw = 0;
#pragma unroll
    for (int q = 0; q < 8; ++q)
        mw |= mask4_s[wave * 8 + q] << (4 * q);
    mw = (uint32_t)__builtin_amdgcn_readfirstlane((int)mw);

    uint2 pjp[BATCH];
    {
        const int j = j0 + wave * 8;
        pjp[0] = ((const uint2*)&pj_h[(size_t)(0 * NN + j) * 128])[lane];
        pjp[1] = ((const uint2*)&pj_h[(size_t)(1 * NN + j) * 128])[lane];
    }

#pragma unroll
    for (int q = 0; q < 8; ++q) {
        const int jl = wave * 8 + q;

        h2v pjr[BATCH][2];
        pjr[0][0] = u2h(pjp[0].x); pjr[0][1] = u2h(pjp[0].y);
        pjr[1][0] = u2h(pjp[1].x); pjr[1][1] = u2h(pjp[1].y);

        if (q < 7) {
            const int j = j0 + jl + 1;
            pjp[0] = ((const uint2*)&pj_h[(size_t)(0 * NN + j) * 128])[lane];
            pjp[1] = ((const uint2*)&pj_h[(size_t)(1 * NN + j) * 128])[lane];
        }

        // fresh per-q accumulators: unconditional init -> stays in VGPRs
        float vals[8] = {0.f, 0.f, 0.f, 0.f, 0.f, 0.f, 0.f, 0.f};

#pragma unroll
        for (int ii = 0; ii < TI; ++ii) {
            if (mw & (1u << (4 * q + ii))) {   // scalar reg test: s_bitcmp+branch
                const uint32_t* erow = &E_s[ii][jl][0];
                const uint4 ua = *(const uint4*)(erow);
                const uint4 ub = *(const uint4*)(erow + 4);
                const uint32_t uc = erow[8];

                h2v pe0, pe1;
                {
                    const h2v e0 = u2h(ua.x), e1 = u2h(ua.y), e2 = u2h(ua.z), e3 = u2h(ua.w);
                    const h2v e4 = u2h(ub.x), e5 = u2h(ub.y), e6 = u2h(ub.z), e7 = u2h(ub.w);
                    const h2v e8 = u2h(uc);
                    pe0 = e0 * wee[0][0];            pe1 = e0 * wee[0][1];
                    pe0 = pe0 + e1 * wee[1][0];      pe1 = pe1 + e1 * wee[1][1];
                    pe0 = pe0 + e2 * wee[2][0];      pe1 = pe1 + e2 * wee[2][1];
                    pe0 = pe0 + e3 * wee[3][0];      pe1 = pe1 + e3 * wee[3][1];
                    pe0 = pe0 + e4 * wee[4][0];      pe1 = pe1 + e4 * wee[4][1];
                    pe0 = pe0 + e5 * wee[5][0];      pe1 = pe1 + e5 * wee[5][1];
                    pe0 = pe0 + e6 * wee[6][0];      pe1 = pe1 + e6 * wee[6][1];
                    pe0 = pe0 + e7 * wee[7][0];      pe1 = pe1 + e7 * wee[7][1];
                    pe0 = pe0 + e8 * wee[8][0];      pe1 = pe1 + e8 * wee[8][1];
                }

#pragma unroll
                for (int b = 0; b < BATCH; ++b) {
                    h2v v0 = relu2(pir[b][ii][0] + pjr[b][0] + pe0);
                    h2v v1 = relu2(pir[b][ii][1] + pjr[b][1] + pe1);
                    vals[2 * ii + b] = fdot2(v1, w2[1], fdot2(v0, w2[0], 0.f));
                }
            }
        }

        // ---- 3-level select+exchange: lane ends with partial of output
        // o = lane&7 over subgroup sub = lane>>3 ----
        float a0, a1, a2, a3;
        {
            const bool b0 = lane & 1;
            float k0 = b0 ? vals[1] : vals[0], s0 = b0 ? vals[0] : vals[1];
            float k1 = b0 ? vals[3] : vals[2], s1 = b0 ? vals[2] : vals[3];
            float k2 = b0 ? vals[5] : vals[4], s2 = b0 ? vals[4] : vals[5];
            float k3 = b0 ? vals[7] : vals[6], s3 = b0 ? vals[6] : vals[7];
            a0 = k0 + __shfl_xor(s0, 1, 64);
            a1 = k1 + __shfl_xor(s1, 1, 64);
            a2 = k2 + __shfl_xor(s2, 1, 64);
            a3 = k3 + __shfl_xor(s3, 1, 64);
        }
        {
            const bool b1 = (lane >> 1) & 1;
            float k0 = b1 ? a1 : a0, s0 = b1 ? a0 : a1;
            float k1 = b1 ? a3 : a2, s1 = b1 ? a2 : a3;
            a0 = k0 + __shfl_xor(s0, 2, 64);
            a1 = k1 + __shfl_xor(s1, 2, 64);
        }
        {
            const bool b2 = (lane >> 2) & 1;
            float k = b2 ? a1 : a0, s = b2 ? a0 : a1;
            a0 = k + __shfl_xor(s, 4, 64);
        }

        // park subgroup partial; all 64 lanes write distinct slots
        part_s[wave][q][lane & 7][lane >> 3] = a0;
    }
    __syncthreads();

    // ---- parallel epilogue: thread t -> (wave w, q, output o) ----
    {
        const int w  = t >> 6;
        const int qq = (t >> 3) & 7;
        const int o  = t & 7;
        const int b  = o & 1;
        const int ii = o >> 1;
        const int jl = w * 8 + qq;
        const int i = i0 + ii, j = j0 + jl;

        const float4 pa = *(const float4*)&part_s[w][qq][o][0];
        const float4 pb = *(const float4*)&part_s[w][qq][o][4];
        const float s = ((pa.x + pa.y) + (pa.z + pa.w))
                      + ((pb.x + pb.y) + (pb.z + pb.w)) + be2[0];
        const float mv = (float)((mask4_s[jl] >> ii) & 1u);
        edge_out[((size_t)b * NN + i) * NN + j] = sigmoidf_(s) * mv;
    }
}

extern "C" void kernel_launch(void* const* d_in, const int* in_sizes, int n_in,
                              void* d_out, int out_size, void* d_ws, size_t ws_size,
                              hipStream_t stream) {
    const float* z    = (const float*)d_in[0];   // (B,N,128)
    const float* E    = (const float*)d_in[1];   // (N,N,9)
    const int*   mask = (const int*)  d_in[2];   // (N,N)
    const float* Wo1  = (const float*)d_in[3];
    const float* bo1  = (const float*)d_in[4];
    const float* Wo2  = (const float*)d_in[5];
    const float* bo2  = (const float*)d_in[6];
    const float* We_i = (const float*)d_in[7];
    const float* We_j = (const float*)d_in[8];
    const float* We_e = (const float*)d_in[9];
    const float* be1  = (const float*)d_in[10];
    const float* We2  = (const float*)d_in[11];
    const float* be2  = (const float*)d_in[12];

    float* out_organ = (float*)d_out;                 // (B,N) = 1024
    float* out_edge  = out_organ + BATCH * NN;        // (B,N,N)

    uint32_t* pi_h = (uint32_t*)d_ws;                        // (B*N,128) half2
    uint32_t* pj_h = pi_h + (size_t)BATCH * NN * (HIDDEN/2); // (B*N,128) half2

    hipLaunchKernelGGL(node_mfma_kernel,
                       dim3(32, 3), dim3(512), 0, stream,
                       z, Wo1, bo1, Wo2, bo2, We_i, We_j, be1,
                       out_organ, pi_h, pj_h);

    hipLaunchKernelGGL(edge_kernel,
                       dim3((NN / TI) * (NN / TJ)), dim3(256), 0, stream,
                       E, mask, We_e, We2, be2, pi_h, pj_h, out_edge);
}